// Round 12
// baseline (208.090 us; speedup 1.0000x reference)
//
#include <hip/hip_runtime.h>
#include <math.h>

#define Bq 4
#define Lq 2048
#define NH 8
#define LDP6 36   // attn Pp row stride (ushorts): 72B = 18 banks, gcd(18,32)=2 -> conflict-free

typedef __attribute__((ext_vector_type(8))) __bf16 bf16x8;
typedef __attribute__((ext_vector_type(4))) float f32x4;
#define MFMA16(a,b,c) __builtin_amdgcn_mfma_f32_16x16x32_bf16(a,b,c,0,0,0)

__device__ __forceinline__ void async16(const void* g, void* l) {
    __builtin_amdgcn_global_load_lds(
        (const __attribute__((address_space(1))) unsigned int*)g,
        (__attribute__((address_space(3))) unsigned int*)l, 16, 0, 0);
}

// truncation split: x = hi + lo (+ ~2^-16 rel residual)
__device__ __forceinline__ void splitbf(float x, ushort& h, ushort& l) {
    unsigned u = __float_as_uint(x);
    h = (ushort)(u >> 16);
    float hf = __uint_as_float(u & 0xffff0000u);
    l = (ushort)(__float_as_uint(x - hf) >> 16);
}
// round-to-nearest-even bf16
__device__ __forceinline__ ushort rnebf(float x) {
    unsigned u = __float_as_uint(x);
    return (ushort)((u + 0x7fffu + ((u >> 16) & 1u)) >> 16);
}

// ---- prep: z=0..3 -> W split (Wq,Wk,Wv,Wo); z=4 -> per-batch mask scan ----
__global__ __launch_bounds__(256) void prep_kernel(
    const float* __restrict__ W0, const float* __restrict__ W1,
    const float* __restrict__ W2, const float* __restrict__ W3,
    ushort* __restrict__ WTh, ushort* __restrict__ WTl,
    const int* __restrict__ mask, int* __restrict__ idx, int* __restrict__ nvalid)
{
    const int tid = threadIdx.x;
    if (blockIdx.z == 4) {
        if (blockIdx.x >= 4 || blockIdx.y != 0) return;
        __shared__ int ss[256];
        const int b = blockIdx.x;
        int m[8], s = 0;
        #pragma unroll
        for (int j = 0; j < 8; ++j) { m[j] = (mask[b * 2048 + tid * 8 + j] != 0); s += m[j]; }
        int v = s;
        ss[tid] = v;
        __syncthreads();
        for (int off = 1; off < 256; off <<= 1) {
            int t_ = (tid >= off) ? ss[tid - off] : 0;
            __syncthreads();
            v += t_;
            ss[tid] = v;
            __syncthreads();
        }
        int pos = v - s;   // exclusive prefix
        #pragma unroll
        for (int j = 0; j < 8; ++j) if (m[j]) idx[b * 2048 + pos++] = tid * 8 + j;
        int tot = ss[255];
        if (tid == 0) nvalid[b] = tot;
        for (int k = tot + tid; k < 2048; k += 256) idx[b * 2048 + k] = 0;  // pad -> row 0
        return;
    }
    __shared__ float T[64][65];
    const int z = blockIdx.z;
    const float* W = (z == 0) ? W0 : (z == 1) ? W1 : (z == 2) ? W2 : W3;
    const int k0 = blockIdx.x * 64, n0 = blockIdx.y * 64;
    #pragma unroll
    for (int i = 0; i < 4; ++i) {
        int u = tid + i * 256;
        int row = u >> 4, c4 = (u & 15) * 4;
        float4 v = *(const float4*)(W + (size_t)(k0 + row) * 512 + n0 + c4);
        T[row][c4 + 0] = v.x; T[row][c4 + 1] = v.y; T[row][c4 + 2] = v.z; T[row][c4 + 3] = v.w;
    }
    __syncthreads();
    #pragma unroll
    for (int i = 0; i < 2; ++i) {
        int u = tid + i * 256;
        int d = u >> 3, c8 = (u & 7) * 8;
        ushort hs[8], ls[8];
        #pragma unroll
        for (int j = 0; j < 8; ++j) splitbf(T[c8 + j][d], hs[j], ls[j]);
        uint4 wh, wl;
        wh.x = hs[0] | ((unsigned)hs[1] << 16); wh.y = hs[2] | ((unsigned)hs[3] << 16);
        wh.z = hs[4] | ((unsigned)hs[5] << 16); wh.w = hs[6] | ((unsigned)hs[7] << 16);
        wl.x = ls[0] | ((unsigned)ls[1] << 16); wl.y = ls[2] | ((unsigned)ls[3] << 16);
        wl.z = ls[4] | ((unsigned)ls[5] << 16); wl.w = ls[6] | ((unsigned)ls[7] << 16);
        size_t off = (size_t)(z * 512 + n0 + d) * 512 + k0 + c8;
        *(uint4*)(WTh + off) = wh;
        *(uint4*)(WTl + off) = wl;
    }
}

// ---- GEMM QKV: 128x128 tile, BK=32, 4 waves (64x64 each) ----
// A path: fp32 X read DIRECTLY (K/V rows gathered through idx), rnebf in
// register, ds_write into swizzled LDS (removes the xrne3 pass entirely).
// B async hi/lo. 32 MFMA/wave/phase. K/V m-blocks early-exit beyond nvpad.
union GS {
    struct {
        ushort A[2][4096];    // 128 rows x 32 k; LDS[row][c] = global chunk c ^ ((row>>1)&3)
        ushort Bh[2][4096];   // 128 cols x 32 k
        ushort Bl[2][4096];
    } s;
    ushort E[24576];          // epilogue scratch (uses 17408)
};

__global__ __launch_bounds__(256) void gemmqkv_kernel(
    const float* __restrict__ Xq, const float* __restrict__ Xk, const float* __restrict__ Xv,
    const int* __restrict__ idx, const int* __restrict__ nvalid,
    const ushort* __restrict__ BhT, const ushort* __restrict__ BlT,
    const float* __restrict__ b0, const float* __restrict__ b1, const float* __restrict__ b2,
    ushort* __restrict__ Qh, ushort* __restrict__ Khp, ushort* __restrict__ VhT)
{
    __shared__ __align__(16) GS gs;
    const int tid = threadIdx.x;
    const int wave = tid >> 6, lane = tid & 63;
    const int l15 = lane & 15, quad = lane >> 4;
    const int m0 = blockIdx.x * 128;
    const int yy = blockIdx.y;
    const int mi = yy >> 2, n0 = (yy & 3) * 128;
    const int nglob = mi * 512 + n0;
    const int b = m0 >> 11;

    if (mi >= 1) {   // uniform early-exit: compacted K/V rows only
        int nv = nvalid[b];
        int nvpad = ((nv + 127) >> 7) << 7;
        if ((m0 & 2047) >= nvpad) return;
    }

    const float* X = (mi == 0) ? Xq : (mi == 1) ? Xk : Xv;
    const float* bias = (mi == 0) ? b0 : (mi == 1) ? b1 : b2;
    const int wm = (wave & 1) * 64, wn = (wave >> 1) * 64;

    // A register staging: thread covers rows am+32i, k-chunk ak (4 floats)
    const int am = tid >> 3, ak = (tid & 7) * 4;
    const float* asrc[4]; int adst[4];
    #pragma unroll
    for (int i = 0; i < 4; ++i) {
        int row = am + 32 * i;
        int grow = m0 + row, r = grow & 2047;
        int srow = (mi == 0) ? grow : (b * 2048 + idx[b * 2048 + r]);
        asrc[i] = X + (size_t)srow * 512 + ak;
        int c = (tid & 7) >> 1;
        int cp = c ^ ((row >> 1) & 3);                // write-side swizzle = read-side
        adst[i] = row * 32 + cp * 8 + (tid & 1) * 4;
    }
    // B staging: 128 rows x 2 planes; wave handles rows wave*32 + j*16 + brow
    const int brow = lane >> 2;
    const int bcs = ((lane & 3) ^ (brow & 3)) * 8;
    const ushort* bsh[2]; const ushort* bsl[2]; int bdst[2];
    #pragma unroll
    for (int j = 0; j < 2; ++j) {
        int r2 = wave * 32 + j * 16 + brow;
        bsh[j] = BhT + (size_t)(nglob + r2) * 512 + bcs;
        bsl[j] = BlT + (size_t)(nglob + r2) * 512 + bcs;
        bdst[j] = wave * 1024 + j * 512 + lane * 8;
    }

    f32x4 acc[4][4];
    #pragma unroll
    for (int i = 0; i < 4; ++i)
        #pragma unroll
        for (int j = 0; j < 4; ++j) acc[i][j] = (f32x4){0.f, 0.f, 0.f, 0.f};

    // prologue: t=0
    float4 av[4];
    #pragma unroll
    for (int i = 0; i < 4; ++i) av[i] = *(const float4*)(asrc[i]);
    #pragma unroll
    for (int j = 0; j < 2; ++j) {
        async16(bsh[j], &gs.s.Bh[0][bdst[j]]);
        async16(bsl[j], &gs.s.Bl[0][bdst[j]]);
    }
    #pragma unroll
    for (int i = 0; i < 4; ++i) {
        ushort4 h4;
        h4.x = rnebf(av[i].x); h4.y = rnebf(av[i].y);
        h4.z = rnebf(av[i].z); h4.w = rnebf(av[i].w);
        *(ushort4*)&gs.s.A[0][adst[i]] = h4;
    }

    for (int t = 0; t < 16; ++t) {
        const int p = t & 1;
        __syncthreads();   // drains async B(t) + A writes(t)
        if (t < 15) {
            const int kn = (t + 1) * 32;
            #pragma unroll
            for (int j = 0; j < 2; ++j) {
                async16(bsh[j] + kn, &gs.s.Bh[1 - p][bdst[j]]);
                async16(bsl[j] + kn, &gs.s.Bl[1 - p][bdst[j]]);
            }
            #pragma unroll
            for (int i = 0; i < 4; ++i) av[i] = *(const float4*)(asrc[i] + kn);
        }
        bf16x8 af[4];
        #pragma unroll
        for (int ms = 0; ms < 4; ++ms) {
            int off = (wm + ms * 16 + l15) * 32 + (quad ^ ((l15 >> 1) & 3)) * 8;
            af[ms] = *(const bf16x8*)&gs.s.A[p][off];
        }
        #pragma unroll
        for (int ns = 0; ns < 4; ++ns) {
            int off = (wn + ns * 16 + l15) * 32 + (quad ^ (l15 & 3)) * 8;
            bf16x8 bfh = *(const bf16x8*)&gs.s.Bh[p][off];
            bf16x8 bfl = *(const bf16x8*)&gs.s.Bl[p][off];
            #pragma unroll
            for (int ms = 0; ms < 4; ++ms) {
                acc[ms][ns] = MFMA16(af[ms], bfl, acc[ms][ns]);
                acc[ms][ns] = MFMA16(af[ms], bfh, acc[ms][ns]);
            }
        }
        if (t < 15) {
            #pragma unroll
            for (int i = 0; i < 4; ++i) {
                ushort4 h4;
                h4.x = rnebf(av[i].x); h4.y = rnebf(av[i].y);
                h4.z = rnebf(av[i].z); h4.w = rnebf(av[i].w);
                *(ushort4*)&gs.s.A[1 - p][adst[i]] = h4;
            }
        }
    }

    // bias
    #pragma unroll
    for (int ns = 0; ns < 4; ++ns) {
        float bv = bias[n0 + wn + ns * 16 + l15];
        #pragma unroll
        for (int ms = 0; ms < 4; ++ms)
            #pragma unroll
            for (int r = 0; r < 4; ++r) acc[ms][ns][r] += bv;
    }

    const int h0 = n0 >> 6;                  // 0,2,4,6 (two heads per block)
    const int rr0 = m0 & 2047;
    __syncthreads();
    // acc -> E, single-pass RNE (V: transposed [col][row]; Q/K: row-major)
    #pragma unroll
    for (int ms = 0; ms < 4; ++ms) {
        #pragma unroll
        for (int ns = 0; ns < 4; ++ns) {
            int cl = wn + ns * 16 + l15;
            int rl = wm + ms * 16 + quad * 4;
            if (mi == 2) {
                ushort4 w4;
                #pragma unroll
                for (int r = 0; r < 4; ++r) ((ushort*)&w4)[r] = rnebf(acc[ms][ns][r]);
                *(ushort4*)&gs.E[cl * 136 + rl] = w4;
            } else {
                #pragma unroll
                for (int r = 0; r < 4; ++r) gs.E[(rl + r) * 136 + cl] = rnebf(acc[ms][ns][r]);
            }
        }
    }
    __syncthreads();
    if (mi == 2) {
        #pragma unroll
        for (int i = 0; i < 8; ++i) {
            int idx2 = tid + i * 256;
            int d = idx2 >> 4, rg = idx2 & 15;
            int head = d >> 6, dd = d & 63;
            uint4 u = *(const uint4*)&gs.E[d * 136 + rg * 8];
            *(uint4*)&VhT[((size_t)(b * 8 + h0 + head) * 64 + dd) * 2048 + rr0 + rg * 8] = u;
        }
    } else {
        ushort* dst = (mi == 0) ? Qh : Khp;
        #pragma unroll
        for (int i = 0; i < 8; ++i) {
            int idx2 = tid + i * 256;
            int row = idx2 >> 4, cg = idx2 & 15;
            int head = cg >> 3, c8 = (cg & 7) * 8;
            uint4 u = *(const uint4*)&gs.E[row * 136 + cg * 8];
            *(uint4*)&dst[((size_t)(b * 8 + h0 + head) * 2048 + rr0 + row) * 64 + c8] = u;
        }
    }
}

// ---- GEMM O: 128x128 tile, A = XS single bf16 plane (async), fp32 out ----
__global__ __launch_bounds__(256) void gemmo_kernel(
    const ushort* __restrict__ Ap,
    const ushort* __restrict__ BhT, const ushort* __restrict__ BlT,
    const float* __restrict__ bias, float* __restrict__ Cf)
{
    __shared__ __align__(16) GS gs;
    const int tid = threadIdx.x;
    const int wave = tid >> 6, lane = tid & 63;
    const int l15 = lane & 15, quad = lane >> 4;
    const int m0 = blockIdx.x * 128;
    const int n0 = blockIdx.y * 128;
    const int wm = (wave & 1) * 64, wn = (wave >> 1) * 64;

    const int arow = lane >> 2;
    const int acs = ((lane & 3) ^ ((arow >> 1) & 3)) * 8;
    const ushort* asrc[2]; int adst[2];
    #pragma unroll
    for (int j = 0; j < 2; ++j) {
        int rb = wave * 2 + j;
        asrc[j] = Ap + (size_t)(m0 + rb * 16 + arow) * 512 + acs;
        adst[j] = rb * 512 + lane * 8;
    }
    const int brow = lane >> 2;
    const int bcs = ((lane & 3) ^ (brow & 3)) * 8;
    const ushort* bsh[2]; const ushort* bsl[2]; int bdst[2];
    #pragma unroll
    for (int j = 0; j < 2; ++j) {
        int r2 = wave * 32 + j * 16 + brow;
        bsh[j] = BhT + (size_t)(n0 + r2) * 512 + bcs;
        bsl[j] = BlT + (size_t)(n0 + r2) * 512 + bcs;
        bdst[j] = wave * 1024 + j * 512 + lane * 8;
    }

    f32x4 acc[4][4];
    #pragma unroll
    for (int i = 0; i < 4; ++i)
        #pragma unroll
        for (int j = 0; j < 4; ++j) acc[i][j] = (f32x4){0.f, 0.f, 0.f, 0.f};

    #pragma unroll
    for (int j = 0; j < 2; ++j) {
        async16(asrc[j], &gs.s.A[0][adst[j]]);
        async16(bsh[j], &gs.s.Bh[0][bdst[j]]);
        async16(bsl[j], &gs.s.Bl[0][bdst[j]]);
    }

    for (int t = 0; t < 16; ++t) {
        const int p = t & 1;
        __syncthreads();
        if (t < 15) {
            const int kn = (t + 1) * 32;
            #pragma unroll
            for (int j = 0; j < 2; ++j) {
                async16(asrc[j] + kn, &gs.s.A[1 - p][adst[j]]);
                async16(bsh[j] + kn, &gs.s.Bh[1 - p][bdst[j]]);
                async16(bsl[j] + kn, &gs.s.Bl[1 - p][bdst[j]]);
            }
        }
        bf16x8 af[4];
        #pragma unroll
        for (int ms = 0; ms < 4; ++ms) {
            int off = (wm + ms * 16 + l15) * 32 + (quad ^ ((l15 >> 1) & 3)) * 8;
            af[ms] = *(const bf16x8*)&gs.s.A[p][off];
        }
        #pragma unroll
        for (int ns = 0; ns < 4; ++ns) {
            int off = (wn + ns * 16 + l15) * 32 + (quad ^ (l15 & 3)) * 8;
            bf16x8 bfh = *(const bf16x8*)&gs.s.Bh[p][off];
            bf16x8 bfl = *(const bf16x8*)&gs.s.Bl[p][off];
            #pragma unroll
            for (int ms = 0; ms < 4; ++ms) {
                acc[ms][ns] = MFMA16(af[ms], bfl, acc[ms][ns]);
                acc[ms][ns] = MFMA16(af[ms], bfh, acc[ms][ns]);
            }
        }
    }

    #pragma unroll
    for (int ns = 0; ns < 4; ++ns) {
        float bv = bias[n0 + wn + ns * 16 + l15];
        #pragma unroll
        for (int ms = 0; ms < 4; ++ms) {
            int col = n0 + wn + ns * 16 + l15;
            #pragma unroll
            for (int r = 0; r < 4; ++r)
                Cf[(size_t)(m0 + wm + ms * 16 + quad * 4 + r) * 512 + col] = acc[ms][ns][r] + bv;
        }
    }
}

// ---- Flash attention over COMPACTED keys, single-plane Q/K/V, RNE XS out ----
union SmemU {
    struct { ushort KVs[2][4][4096]; ushort Pp[8][64 * LDP6]; } p1;
    struct { float Obuf[4][64 * 68]; float Lbuf[4][64]; } p2;
};

__global__ __launch_bounds__(512, 2) void attn3_kernel(
    const ushort* __restrict__ Qh, const ushort* __restrict__ Kh,
    const ushort* __restrict__ VhT, const int* __restrict__ nvalid,
    ushort* __restrict__ XS)
{
    __shared__ SmemU smem;
    const int tid = threadIdx.x;
    const int wave = tid >> 6, lane = tid & 63;
    const int l15 = lane & 15, quad = lane >> 4;
    const int w4 = wave & 3, half = wave >> 2;
    const int bh = blockIdx.x, b = bh >> 3, h = bh & 7;
    const int q0 = blockIdx.y * 256;

    const int nv = nvalid[b];
    const int nt = (nv + 127) >> 7;      // tiles per half
    const int kvofs = half * 64 * nt;    // this wave's compacted-key offset

    bf16x8 qf[4][2];
    #pragma unroll
    for (int qs = 0; qs < 4; ++qs) {
        size_t qb = ((size_t)bh * 2048 + q0 + w4 * 64 + qs * 16 + l15) * 64 + quad * 8;
        qf[qs][0] = *(const bf16x8*)(Qh + qb);
        qf[qs][1] = *(const bf16x8*)(Qh + qb + 32);
    }

    const f32x4 z = {0.f, 0.f, 0.f, 0.f};
    f32x4 oacc[4][4];
    #pragma unroll
    for (int i = 0; i < 4; ++i)
        #pragma unroll
        for (int j = 0; j < 4; ++j) oacc[i][j] = z;
    float lacc[4] = {0.f, 0.f, 0.f, 0.f};

    const int rloc = lane >> 3, gsw = (lane & 7) ^ rloc;
    const ushort* sb[4]; size_t sstep[4]; int dofs[4];
    #pragma unroll
    for (int i = 0; i < 4; ++i) {
        int cc = wave * 4 + i;
        int hc = cc >> 4, r16 = cc & 15, pc = r16 >> 3, ic = r16 & 7;
        if (pc == 0) {
            sb[i] = Kh + ((size_t)(bh * 2048 + hc * 64 * nt + ic * 8 + rloc)) * 64 + gsw * 8;
            sstep[i] = (size_t)64 * 64;
        } else {
            sb[i] = VhT + ((size_t)(bh * 64 + ic * 8 + rloc)) * 2048 + hc * 64 * nt + gsw * 8;
            sstep[i] = 64;
        }
        dofs[i] = (hc * 2 + pc) * 4096 + ic * 512;
    }

    const int sw0 = (quad ^ (l15 & 7)) * 8;
    const float SCL = 0.18033688011112042f;   // 0.125 * log2(e)

    if (nt > 0) {
        #pragma unroll
        for (int i = 0; i < 4; ++i)
            async16(sb[i], &smem.p1.KVs[0][0][0] + dofs[i]);
    }

    for (int t = 0; t < nt; ++t) {
        __syncthreads();
        if (t + 1 < nt) {
            #pragma unroll
            for (int i = 0; i < 4; ++i)
                async16(sb[i] + (size_t)(t + 1) * sstep[i], &smem.p1.KVs[(t + 1) & 1][0][0] + dofs[i]);
        }
        const int p = t & 1;
        const ushort* K0 = smem.p1.KVs[p][half * 2 + 0];
        const ushort* V0 = smem.p1.KVs[p][half * 2 + 1];
        ushort* Pw = smem.p1.Pp[wave];

        #pragma unroll
        for (int ks = 0; ks < 2; ++ks) {
            #pragma unroll
            for (int kt2 = 0; kt2 < 2; ++kt2) {
                const int kt = ks * 2 + kt2;
                const int kb = (kt * 16 + l15) * 64;
                bf16x8 ka0 = *(const bf16x8*)&K0[kb + sw0];
                bf16x8 ka1 = *(const bf16x8*)&K0[kb + (sw0 ^ 32)];
                const int kbase = kvofs + t * 64 + kt * 16 + quad * 4;
                float bias[4];   // log2-domain tail bias (replaces mask loads)
                #pragma unroll
                for (int r = 0; r < 4; ++r) bias[r] = (kbase + r < nv) ? 0.f : -1e38f;
                #pragma unroll
                for (int qs = 0; qs < 4; ++qs) {
                    f32x4 a = z;
                    a = MFMA16(ka0, qf[qs][0], a);
                    a = MFMA16(ka1, qf[qs][1], a);
                    float pv[4];
                    #pragma unroll
                    for (int r = 0; r < 4; ++r) {
                        float x = __builtin_fmaf(a[r], SCL, bias[r]);
                        float e; asm("v_exp_f32 %0, %1" : "=v"(e) : "v"(x));
                        lacc[qs] += e;
                        pv[r] = e;
                    }
                    unsigned u01, u23;
                    asm("v_cvt_pk_bf16_f32 %0, %1, %2" : "=v"(u01) : "v"(pv[0]), "v"(pv[1]));
                    asm("v_cvt_pk_bf16_f32 %0, %1, %2" : "=v"(u23) : "v"(pv[2]), "v"(pv[3]));
                    uint2 w2; w2.x = u01; w2.y = u23;
                    *(uint2*)&Pw[(qs * 16 + l15) * LDP6 + kt2 * 16 + quad * 4] = w2;
                }
            }
            const int svo = sw0 ^ (ks * 32);
            bf16x8 pf[4];
            #pragma unroll
            for (int qs = 0; qs < 4; ++qs)
                pf[qs] = *(const bf16x8*)&Pw[(qs * 16 + l15) * LDP6 + quad * 8];
            #pragma unroll
            for (int dsub = 0; dsub < 4; ++dsub) {
                const int vb = (dsub * 16 + l15) * 64;
                bf16x8 vh = *(const bf16x8*)&V0[vb + svo];
                #pragma unroll
                for (int qs = 0; qs < 4; ++qs)
                    oacc[qs][dsub] = MFMA16(vh, pf[qs], oacc[qs][dsub]);
            }
        }
    }

    float lv[4];
    #pragma unroll
    for (int qs = 0; qs < 4; ++qs) {
        float v = lacc[qs];
        v += __shfl_xor(v, 16);
        v += __shfl_xor(v, 32);
        lv[qs] = v;
    }

    __syncthreads();
    if (half == 1) {
        #pragma unroll
        for (int qs = 0; qs < 4; ++qs) {
            #pragma unroll
            for (int dsub = 0; dsub < 4; ++dsub) {
                float4 o4 = {oacc[qs][dsub][0], oacc[qs][dsub][1], oacc[qs][dsub][2], oacc[qs][dsub][3]};
                *(float4*)&smem.p2.Obuf[w4][(qs * 16 + l15) * 68 + dsub * 16 + quad * 4] = o4;
            }
            if (quad == 0) smem.p2.Lbuf[w4][qs * 16 + l15] = lv[qs];
        }
    }
    __syncthreads();
    if (half == 0) {
        #pragma unroll
        for (int qs = 0; qs < 4; ++qs) {
            float ltot = lv[qs] + smem.p2.Lbuf[w4][qs * 16 + l15];
            float inv = (ltot > 0.f) ? 1.f / ltot : 0.f;
            int row = q0 + w4 * 64 + qs * 16 + l15;
            ushort* rp = XS + ((size_t)(b * 2048 + row)) * 512 + h * 64;
            #pragma unroll
            for (int dsub = 0; dsub < 4; ++dsub) {
                float4 p4 = *(const float4*)&smem.p2.Obuf[w4][(qs * 16 + l15) * 68 + dsub * 16 + quad * 4];
                ushort4 hv;
                hv.x = rnebf((oacc[qs][dsub][0] + p4.x) * inv);
                hv.y = rnebf((oacc[qs][dsub][1] + p4.y) * inv);
                hv.z = rnebf((oacc[qs][dsub][2] + p4.z) * inv);
                hv.w = rnebf((oacc[qs][dsub][3] + p4.w) * inv);
                *(ushort4*)&rp[dsub * 16 + quad * 4] = hv;
            }
        }
    }
}

extern "C" void kernel_launch(void* const* d_in, const int* in_sizes, int n_in,
                              void* d_out, int out_size, void* d_ws, size_t ws_size,
                              hipStream_t stream) {
    const float* query = (const float*)d_in[0];
    const float* key   = (const float*)d_in[1];
    const float* value = (const float*)d_in[2];
    const int*   mask  = (const int*)d_in[3];
    const float* Wq = (const float*)d_in[4];
    const float* bq = (const float*)d_in[5];
    const float* Wk = (const float*)d_in[6];
    const float* bk = (const float*)d_in[7];
    const float* Wv = (const float*)d_in[8];
    const float* bv = (const float*)d_in[9];
    const float* Wo = (const float*)d_in[10];
    const float* bo = (const float*)d_in[11];

    char* w = (char*)d_ws;
    const size_t MB = (size_t)1 << 20;
    ushort* Qh  = (ushort*)(w + 0 * MB);    // 8 MB
    ushort* XS  = (ushort*)(w + 8 * MB);    // 8 MB (attn out, single RNE plane)
    ushort* Khp = (ushort*)(w + 16 * MB);   // 8 MB
    ushort* VhT = (ushort*)(w + 24 * MB);   // 8 MB
    ushort* WTh = (ushort*)(w + 32 * MB);   // [2048][512] = 2 MB (z=0..3: Wq,Wk,Wv,Wo)
    ushort* WTl = (ushort*)(w + 34 * MB);   // 2 MB
    int* idxbuf = (int*)(w + 36 * MB);      // [4][2048] int, 32 KB
    int* nvbuf  = (int*)(w + 36 * MB + 65536);

    prep_kernel<<<dim3(8, 8, 5), 256, 0, stream>>>(
        Wq, Wk, Wv, Wo, WTh, WTl, mask, idxbuf, nvbuf);
    gemmqkv_kernel<<<dim3(64, 12), 256, 0, stream>>>(
        query, key, value, idxbuf, nvbuf, WTh, WTl, bq, bk, bv, Qh, Khp, VhT);
    attn3_kernel<<<dim3(32, 8), 512, 0, stream>>>(Qh, Khp, VhT, nvbuf, XS);
    gemmo_kernel<<<dim3(64, 4), 256, 0, stream>>>(
        XS, WTh + (size_t)1536 * 512, WTl + (size_t)1536 * 512, bo, (float*)d_out);
}

// Round 13
// 184.752 us; speedup vs baseline: 1.1263x; 1.1263x over previous
//
#include <hip/hip_runtime.h>
#include <math.h>

#define Bq 4
#define Lq 2048
#define NH 8
#define LDP6 36   // attn Pp row stride (ushorts): 72B = 18 banks, gcd(18,32)=2 -> conflict-free

typedef __attribute__((ext_vector_type(8))) __bf16 bf16x8;
typedef __attribute__((ext_vector_type(4))) float f32x4;
#define MFMA16(a,b,c) __builtin_amdgcn_mfma_f32_16x16x32_bf16(a,b,c,0,0,0)

__device__ __forceinline__ void async16(const void* g, void* l) {
    __builtin_amdgcn_global_load_lds(
        (const __attribute__((address_space(1))) unsigned int*)g,
        (__attribute__((address_space(3))) unsigned int*)l, 16, 0, 0);
}

// truncation split: x = hi + lo (+ ~2^-16 rel residual)
__device__ __forceinline__ void splitbf(float x, ushort& h, ushort& l) {
    unsigned u = __float_as_uint(x);
    h = (ushort)(u >> 16);
    float hf = __uint_as_float(u & 0xffff0000u);
    l = (ushort)(__float_as_uint(x - hf) >> 16);
}
// round-to-nearest-even bf16
__device__ __forceinline__ ushort rnebf(float x) {
    unsigned u = __float_as_uint(x);
    return (ushort)((u + 0x7fffu + ((u >> 16) & 1u)) >> 16);
}

// ---- prep (one launch, all independent):
//   z=0..2 : X (q,k,v) fp32 -> Xr single RNE bf16 plane (no gather)
//   z=3, x<256    : W split (x>>6 selects Wq/Wk/Wv/Wo) -> WTh/WTl
//   z=3, 256<=x<260: per-batch mask scan -> idx, nvalid
__global__ __launch_bounds__(256) void prep_kernel(
    const float* __restrict__ W0, const float* __restrict__ W1,
    const float* __restrict__ W2, const float* __restrict__ W3,
    ushort* __restrict__ WTh, ushort* __restrict__ WTl,
    const int* __restrict__ mask, int* __restrict__ idx, int* __restrict__ nvalid,
    const float* __restrict__ X0, const float* __restrict__ X1, const float* __restrict__ X2,
    ushort* __restrict__ Xr)
{
    const int tid = threadIdx.x;
    const int z = blockIdx.z;
    if (z < 3) {   // xrne: 2048 blocks x 2048 elems
        const float* X = (z == 0) ? X0 : (z == 1) ? X1 : X2;
        const size_t ebase = (size_t)blockIdx.x * 2048 + (size_t)tid * 8;
        float4 a = *(const float4*)(X + ebase);
        float4 bb = *(const float4*)(X + ebase + 4);
        float vv[8] = {a.x, a.y, a.z, a.w, bb.x, bb.y, bb.z, bb.w};
        ushort hs[8];
        #pragma unroll
        for (int j = 0; j < 8; ++j) hs[j] = rnebf(vv[j]);
        uint4 wh;
        wh.x = hs[0] | ((unsigned)hs[1] << 16); wh.y = hs[2] | ((unsigned)hs[3] << 16);
        wh.z = hs[4] | ((unsigned)hs[5] << 16); wh.w = hs[6] | ((unsigned)hs[7] << 16);
        *(uint4*)(Xr + (size_t)z * 8192 * 512 + ebase) = wh;
        return;
    }
    const int x = blockIdx.x;
    __shared__ float T[64][65];
    __shared__ int ss[256];
    if (x < 256) {   // W split
        const int m = x >> 6;
        const float* W = (m == 0) ? W0 : (m == 1) ? W1 : (m == 2) ? W2 : W3;
        const int k0 = ((x >> 3) & 7) * 64, n0 = (x & 7) * 64;
        #pragma unroll
        for (int i = 0; i < 4; ++i) {
            int u = tid + i * 256;
            int row = u >> 4, c4 = (u & 15) * 4;
            float4 v = *(const float4*)(W + (size_t)(k0 + row) * 512 + n0 + c4);
            T[row][c4 + 0] = v.x; T[row][c4 + 1] = v.y; T[row][c4 + 2] = v.z; T[row][c4 + 3] = v.w;
        }
        __syncthreads();
        #pragma unroll
        for (int i = 0; i < 2; ++i) {
            int u = tid + i * 256;
            int d = u >> 3, c8 = (u & 7) * 8;
            ushort hs[8], ls[8];
            #pragma unroll
            for (int j = 0; j < 8; ++j) splitbf(T[c8 + j][d], hs[j], ls[j]);
            uint4 wh, wl;
            wh.x = hs[0] | ((unsigned)hs[1] << 16); wh.y = hs[2] | ((unsigned)hs[3] << 16);
            wh.z = hs[4] | ((unsigned)hs[5] << 16); wh.w = hs[6] | ((unsigned)hs[7] << 16);
            wl.x = ls[0] | ((unsigned)ls[1] << 16); wl.y = ls[2] | ((unsigned)ls[3] << 16);
            wl.z = ls[4] | ((unsigned)ls[5] << 16); wl.w = ls[6] | ((unsigned)ls[7] << 16);
            size_t off = (size_t)(m * 512 + n0 + d) * 512 + k0 + c8;
            *(uint4*)(WTh + off) = wh;
            *(uint4*)(WTl + off) = wl;
        }
        return;
    }
    if (x < 260) {   // mask scan
        const int b = x - 256;
        int m[8], s = 0;
        #pragma unroll
        for (int j = 0; j < 8; ++j) { m[j] = (mask[b * 2048 + tid * 8 + j] != 0); s += m[j]; }
        int v = s;
        ss[tid] = v;
        __syncthreads();
        for (int off = 1; off < 256; off <<= 1) {
            int t_ = (tid >= off) ? ss[tid - off] : 0;
            __syncthreads();
            v += t_;
            ss[tid] = v;
            __syncthreads();
        }
        int pos = v - s;   // exclusive prefix
        #pragma unroll
        for (int j = 0; j < 8; ++j) if (m[j]) idx[b * 2048 + pos++] = tid * 8 + j;
        int tot = ss[255];
        if (tid == 0) nvalid[b] = tot;
        for (int k = tot + tid; k < 2048; k += 256) idx[b * 2048 + k] = 0;  // pad -> row 0
    }
}

// ---- GEMM QKV: 128x128 tile, BK=32, 4 waves (64x64 each), fully-async ----
// A: single bf16 plane, K/V rows GATHERED at the async16 source (per-lane
// global addr; row fixed per thread across K). B: single plane (WTh only) ->
// 16 MFMA/wave/phase, 16KB staged/phase, LDS 34KB (4 blocks/CU).
union GS {
    struct {
        ushort A[2][4096];    // 128 rows x 32 k; LDS[row][c] = global chunk c ^ ((row>>1)&3)
        ushort B[2][4096];    // 128 cols x 32 k; LDS[col][c] = global chunk c ^ (col&3)
    } s;
    ushort E[17408];          // epilogue scratch
};

__global__ __launch_bounds__(256) void gemmqkv_kernel(
    const ushort* __restrict__ Xr,
    const int* __restrict__ idx, const int* __restrict__ nvalid,
    const ushort* __restrict__ BT,
    const float* __restrict__ b0, const float* __restrict__ b1, const float* __restrict__ b2,
    ushort* __restrict__ Qh, ushort* __restrict__ Khp, ushort* __restrict__ VhT)
{
    __shared__ __align__(16) GS gs;
    const int tid = threadIdx.x;
    const int wave = tid >> 6, lane = tid & 63;
    const int l15 = lane & 15, quad = lane >> 4;
    const int m0 = blockIdx.x * 128;
    const int yy = blockIdx.y;
    const int mi = yy >> 2, n0 = (yy & 3) * 128;
    const int nglob = mi * 512 + n0;
    const int b = m0 >> 11;

    if (mi >= 1) {   // uniform early-exit: compacted K/V rows only
        int nv = nvalid[b];
        int nvpad = ((nv + 127) >> 7) << 7;
        if ((m0 & 2047) >= nvpad) return;
    }

    const float* bias = (mi == 0) ? b0 : (mi == 1) ? b1 : b2;
    const int wm = (wave & 1) * 64, wn = (wave >> 1) * 64;

    // A async staging (gathered): wave covers rowblocks rb = wave*2 + j
    const ushort* AZ = Xr + (size_t)mi * 8192 * 512;
    const int arow = lane >> 2;
    const int acs = ((lane & 3) ^ ((arow >> 1) & 3)) * 8;   // src pre-swizzle = read swizzle
    const ushort* asrc[2]; int adst[2];
    #pragma unroll
    for (int j = 0; j < 2; ++j) {
        int rb = wave * 2 + j;
        int row = rb * 16 + arow;
        int grow = m0 + row, r = grow & 2047;
        int srow = (mi == 0) ? grow : (b * 2048 + idx[b * 2048 + r]);
        asrc[j] = AZ + (size_t)srow * 512 + acs;
        adst[j] = rb * 512 + lane * 8;
    }
    // B async staging (single plane)
    const int brow = lane >> 2;
    const int bcs = ((lane & 3) ^ (brow & 3)) * 8;
    const ushort* bsp[2]; int bdst[2];
    #pragma unroll
    for (int j = 0; j < 2; ++j) {
        int r2 = wave * 32 + j * 16 + brow;
        bsp[j] = BT + (size_t)(nglob + r2) * 512 + bcs;
        bdst[j] = wave * 1024 + j * 512 + lane * 8;
    }

    f32x4 acc[4][4];
    #pragma unroll
    for (int i = 0; i < 4; ++i)
        #pragma unroll
        for (int j = 0; j < 4; ++j) acc[i][j] = (f32x4){0.f, 0.f, 0.f, 0.f};

    #pragma unroll
    for (int j = 0; j < 2; ++j) {
        async16(asrc[j], &gs.s.A[0][adst[j]]);
        async16(bsp[j], &gs.s.B[0][bdst[j]]);
    }

    for (int t = 0; t < 16; ++t) {
        const int p = t & 1;
        __syncthreads();
        if (t < 15) {
            const int kn = (t + 1) * 32;
            #pragma unroll
            for (int j = 0; j < 2; ++j) {
                async16(asrc[j] + kn, &gs.s.A[1 - p][adst[j]]);
                async16(bsp[j] + kn, &gs.s.B[1 - p][bdst[j]]);
            }
        }
        bf16x8 af[4];
        #pragma unroll
        for (int ms = 0; ms < 4; ++ms) {
            int off = (wm + ms * 16 + l15) * 32 + (quad ^ ((l15 >> 1) & 3)) * 8;
            af[ms] = *(const bf16x8*)&gs.s.A[p][off];
        }
        #pragma unroll
        for (int ns = 0; ns < 4; ++ns) {
            int off = (wn + ns * 16 + l15) * 32 + (quad ^ (l15 & 3)) * 8;
            bf16x8 bf = *(const bf16x8*)&gs.s.B[p][off];
            #pragma unroll
            for (int ms = 0; ms < 4; ++ms)
                acc[ms][ns] = MFMA16(af[ms], bf, acc[ms][ns]);
        }
    }

    // bias
    #pragma unroll
    for (int ns = 0; ns < 4; ++ns) {
        float bv = bias[n0 + wn + ns * 16 + l15];
        #pragma unroll
        for (int ms = 0; ms < 4; ++ms)
            #pragma unroll
            for (int r = 0; r < 4; ++r) acc[ms][ns][r] += bv;
    }

    const int h0 = n0 >> 6;                  // 0,2,4,6 (two heads per block)
    const int rr0 = m0 & 2047;
    __syncthreads();
    // acc -> E, single-pass RNE (V: transposed [col][row]; Q/K: row-major)
    #pragma unroll
    for (int ms = 0; ms < 4; ++ms) {
        #pragma unroll
        for (int ns = 0; ns < 4; ++ns) {
            int cl = wn + ns * 16 + l15;
            int rl = wm + ms * 16 + quad * 4;
            if (mi == 2) {
                ushort4 w4;
                #pragma unroll
                for (int r = 0; r < 4; ++r) ((ushort*)&w4)[r] = rnebf(acc[ms][ns][r]);
                *(ushort4*)&gs.E[cl * 136 + rl] = w4;
            } else {
                #pragma unroll
                for (int r = 0; r < 4; ++r) gs.E[(rl + r) * 136 + cl] = rnebf(acc[ms][ns][r]);
            }
        }
    }
    __syncthreads();
    if (mi == 2) {
        #pragma unroll
        for (int i = 0; i < 8; ++i) {
            int idx2 = tid + i * 256;
            int d = idx2 >> 4, rg = idx2 & 15;
            int head = d >> 6, dd = d & 63;
            uint4 u = *(const uint4*)&gs.E[d * 136 + rg * 8];
            *(uint4*)&VhT[((size_t)(b * 8 + h0 + head) * 64 + dd) * 2048 + rr0 + rg * 8] = u;
        }
    } else {
        ushort* dst = (mi == 0) ? Qh : Khp;
        #pragma unroll
        for (int i = 0; i < 8; ++i) {
            int idx2 = tid + i * 256;
            int row = idx2 >> 4, cg = idx2 & 15;
            int head = cg >> 3, c8 = (cg & 7) * 8;
            uint4 u = *(const uint4*)&gs.E[row * 136 + cg * 8];
            *(uint4*)&dst[((size_t)(b * 8 + h0 + head) * 2048 + rr0 + row) * 64 + c8] = u;
        }
    }
}

// ---- GEMM O: 128x128 tile, A = XS single bf16 plane (async), B hi/lo, fp32 out ----
union GSO {
    struct {
        ushort A[2][4096];
        ushort Bh[2][4096];
        ushort Bl[2][4096];
    } s;
};

__global__ __launch_bounds__(256) void gemmo_kernel(
    const ushort* __restrict__ Ap,
    const ushort* __restrict__ BhT, const ushort* __restrict__ BlT,
    const float* __restrict__ bias, float* __restrict__ Cf)
{
    __shared__ __align__(16) GSO gs;
    const int tid = threadIdx.x;
    const int wave = tid >> 6, lane = tid & 63;
    const int l15 = lane & 15, quad = lane >> 4;
    const int m0 = blockIdx.x * 128;
    const int n0 = blockIdx.y * 128;
    const int wm = (wave & 1) * 64, wn = (wave >> 1) * 64;

    const int arow = lane >> 2;
    const int acs = ((lane & 3) ^ ((arow >> 1) & 3)) * 8;
    const ushort* asrc[2]; int adst[2];
    #pragma unroll
    for (int j = 0; j < 2; ++j) {
        int rb = wave * 2 + j;
        asrc[j] = Ap + (size_t)(m0 + rb * 16 + arow) * 512 + acs;
        adst[j] = rb * 512 + lane * 8;
    }
    const int brow = lane >> 2;
    const int bcs = ((lane & 3) ^ (brow & 3)) * 8;
    const ushort* bsh[2]; const ushort* bsl[2]; int bdst[2];
    #pragma unroll
    for (int j = 0; j < 2; ++j) {
        int r2 = wave * 32 + j * 16 + brow;
        bsh[j] = BhT + (size_t)(n0 + r2) * 512 + bcs;
        bsl[j] = BlT + (size_t)(n0 + r2) * 512 + bcs;
        bdst[j] = wave * 1024 + j * 512 + lane * 8;
    }

    f32x4 acc[4][4];
    #pragma unroll
    for (int i = 0; i < 4; ++i)
        #pragma unroll
        for (int j = 0; j < 4; ++j) acc[i][j] = (f32x4){0.f, 0.f, 0.f, 0.f};

    #pragma unroll
    for (int j = 0; j < 2; ++j) {
        async16(asrc[j], &gs.s.A[0][adst[j]]);
        async16(bsh[j], &gs.s.Bh[0][bdst[j]]);
        async16(bsl[j], &gs.s.Bl[0][bdst[j]]);
    }

    for (int t = 0; t < 16; ++t) {
        const int p = t & 1;
        __syncthreads();
        if (t < 15) {
            const int kn = (t + 1) * 32;
            #pragma unroll
            for (int j = 0; j < 2; ++j) {
                async16(asrc[j] + kn, &gs.s.A[1 - p][adst[j]]);
                async16(bsh[j] + kn, &gs.s.Bh[1 - p][bdst[j]]);
                async16(bsl[j] + kn, &gs.s.Bl[1 - p][bdst[j]]);
            }
        }
        bf16x8 af[4];
        #pragma unroll
        for (int ms = 0; ms < 4; ++ms) {
            int off = (wm + ms * 16 + l15) * 32 + (quad ^ ((l15 >> 1) & 3)) * 8;
            af[ms] = *(const bf16x8*)&gs.s.A[p][off];
        }
        #pragma unroll
        for (int ns = 0; ns < 4; ++ns) {
            int off = (wn + ns * 16 + l15) * 32 + (quad ^ (l15 & 3)) * 8;
            bf16x8 bfh = *(const bf16x8*)&gs.s.Bh[p][off];
            bf16x8 bfl = *(const bf16x8*)&gs.s.Bl[p][off];
            #pragma unroll
            for (int ms = 0; ms < 4; ++ms) {
                acc[ms][ns] = MFMA16(af[ms], bfl, acc[ms][ns]);
                acc[ms][ns] = MFMA16(af[ms], bfh, acc[ms][ns]);
            }
        }
    }

    #pragma unroll
    for (int ns = 0; ns < 4; ++ns) {
        float bv = bias[n0 + wn + ns * 16 + l15];
        #pragma unroll
        for (int ms = 0; ms < 4; ++ms) {
            int col = n0 + wn + ns * 16 + l15;
            #pragma unroll
            for (int r = 0; r < 4; ++r)
                Cf[(size_t)(m0 + wm + ms * 16 + quad * 4 + r) * 512 + col] = acc[ms][ns][r] + bv;
        }
    }
}

// ---- Flash attention over COMPACTED keys, single-plane Q/K/V, RNE XS out ----
union SmemU {
    struct { ushort KVs[2][4][4096]; ushort Pp[8][64 * LDP6]; } p1;
    struct { float Obuf[4][64 * 68]; float Lbuf[4][64]; } p2;
};

__global__ __launch_bounds__(512, 2) void attn3_kernel(
    const ushort* __restrict__ Qh, const ushort* __restrict__ Kh,
    const ushort* __restrict__ VhT, const int* __restrict__ nvalid,
    ushort* __restrict__ XS)
{
    __shared__ SmemU smem;
    const int tid = threadIdx.x;
    const int wave = tid >> 6, lane = tid & 63;
    const int l15 = lane & 15, quad = lane >> 4;
    const int w4 = wave & 3, half = wave >> 2;
    const int bh = blockIdx.x, b = bh >> 3, h = bh & 7;
    const int q0 = blockIdx.y * 256;

    const int nv = nvalid[b];
    const int nt = (nv + 127) >> 7;      // tiles per half
    const int kvofs = half * 64 * nt;    // this wave's compacted-key offset

    bf16x8 qf[4][2];
    #pragma unroll
    for (int qs = 0; qs < 4; ++qs) {
        size_t qb = ((size_t)bh * 2048 + q0 + w4 * 64 + qs * 16 + l15) * 64 + quad * 8;
        qf[qs][0] = *(const bf16x8*)(Qh + qb);
        qf[qs][1] = *(const bf16x8*)(Qh + qb + 32);
    }

    const f32x4 z = {0.f, 0.f, 0.f, 0.f};
    f32x4 oacc[4][4];
    #pragma unroll
    for (int i = 0; i < 4; ++i)
        #pragma unroll
        for (int j = 0; j < 4; ++j) oacc[i][j] = z;
    float lacc[4] = {0.f, 0.f, 0.f, 0.f};

    const int rloc = lane >> 3, gsw = (lane & 7) ^ rloc;
    const ushort* sb[4]; size_t sstep[4]; int dofs[4];
    #pragma unroll
    for (int i = 0; i < 4; ++i) {
        int cc = wave * 4 + i;
        int hc = cc >> 4, r16 = cc & 15, pc = r16 >> 3, ic = r16 & 7;
        if (pc == 0) {
            sb[i] = Kh + ((size_t)(bh * 2048 + hc * 64 * nt + ic * 8 + rloc)) * 64 + gsw * 8;
            sstep[i] = (size_t)64 * 64;
        } else {
            sb[i] = VhT + ((size_t)(bh * 64 + ic * 8 + rloc)) * 2048 + hc * 64 * nt + gsw * 8;
            sstep[i] = 64;
        }
        dofs[i] = (hc * 2 + pc) * 4096 + ic * 512;
    }

    const int sw0 = (quad ^ (l15 & 7)) * 8;
    const float SCL = 0.18033688011112042f;   // 0.125 * log2(e)

    if (nt > 0) {
        #pragma unroll
        for (int i = 0; i < 4; ++i)
            async16(sb[i], &smem.p1.KVs[0][0][0] + dofs[i]);
    }

    for (int t = 0; t < nt; ++t) {
        __syncthreads();
        if (t + 1 < nt) {
            #pragma unroll
            for (int i = 0; i < 4; ++i)
                async16(sb[i] + (size_t)(t + 1) * sstep[i], &smem.p1.KVs[(t + 1) & 1][0][0] + dofs[i]);
        }
        const int p = t & 1;
        const ushort* K0 = smem.p1.KVs[p][half * 2 + 0];
        const ushort* V0 = smem.p1.KVs[p][half * 2 + 1];
        ushort* Pw = smem.p1.Pp[wave];

        #pragma unroll
        for (int ks = 0; ks < 2; ++ks) {
            #pragma unroll
            for (int kt2 = 0; kt2 < 2; ++kt2) {
                const int kt = ks * 2 + kt2;
                const int kb = (kt * 16 + l15) * 64;
                bf16x8 ka0 = *(const bf16x8*)&K0[kb + sw0];
                bf16x8 ka1 = *(const bf16x8*)&K0[kb + (sw0 ^ 32)];
                const int kbase = kvofs + t * 64 + kt * 16 + quad * 4;
                float bias[4];   // log2-domain tail bias (replaces mask loads)
                #pragma unroll
                for (int r = 0; r < 4; ++r) bias[r] = (kbase + r < nv) ? 0.f : -1e38f;
                #pragma unroll
                for (int qs = 0; qs < 4; ++qs) {
                    f32x4 a = z;
                    a = MFMA16(ka0, qf[qs][0], a);
                    a = MFMA16(ka1, qf[qs][1], a);
                    float pv[4];
                    #pragma unroll
                    for (int r = 0; r < 4; ++r) {
                        float x = __builtin_fmaf(a[r], SCL, bias[r]);
                        float e; asm("v_exp_f32 %0, %1" : "=v"(e) : "v"(x));
                        lacc[qs] += e;
                        pv[r] = e;
                    }
                    unsigned u01, u23;
                    asm("v_cvt_pk_bf16_f32 %0, %1, %2" : "=v"(u01) : "v"(pv[0]), "v"(pv[1]));
                    asm("v_cvt_pk_bf16_f32 %0, %1, %2" : "=v"(u23) : "v"(pv[2]), "v"(pv[3]));
                    uint2 w2; w2.x = u01; w2.y = u23;
                    *(uint2*)&Pw[(qs * 16 + l15) * LDP6 + kt2 * 16 + quad * 4] = w2;
                }
            }
            const int svo = sw0 ^ (ks * 32);
            bf16x8 pf[4];
            #pragma unroll
            for (int qs = 0; qs < 4; ++qs)
                pf[qs] = *(const bf16x8*)&Pw[(qs * 16 + l15) * LDP6 + quad * 8];
            #pragma unroll
            for (int dsub = 0; dsub < 4; ++dsub) {
                const int vb = (dsub * 16 + l15) * 64;
                bf16x8 vh = *(const bf16x8*)&V0[vb + svo];
                #pragma unroll
                for (int qs = 0; qs < 4; ++qs)
                    oacc[qs][dsub] = MFMA16(vh, pf[qs], oacc[qs][dsub]);
            }
        }
    }

    float lv[4];
    #pragma unroll
    for (int qs = 0; qs < 4; ++qs) {
        float v = lacc[qs];
        v += __shfl_xor(v, 16);
        v += __shfl_xor(v, 32);
        lv[qs] = v;
    }

    __syncthreads();
    if (half == 1) {
        #pragma unroll
        for (int qs = 0; qs < 4; ++qs) {
            #pragma unroll
            for (int dsub = 0; dsub < 4; ++dsub) {
                float4 o4 = {oacc[qs][dsub][0], oacc[qs][dsub][1], oacc[qs][dsub][2], oacc[qs][dsub][3]};
                *(float4*)&smem.p2.Obuf[w4][(qs * 16 + l15) * 68 + dsub * 16 + quad * 4] = o4;
            }
            if (quad == 0) smem.p2.Lbuf[w4][qs * 16 + l15] = lv[qs];
        }
    }
    __syncthreads();
    if (half == 0) {
        #pragma unroll
        for (int qs = 0; qs < 4; ++qs) {
            float ltot = lv[qs] + smem.p2.Lbuf[w4][qs * 16 + l15];
            float inv = (ltot > 0.f) ? 1.f / ltot : 0.f;
            int row = q0 + w4 * 64 + qs * 16 + l15;
            ushort* rp = XS + ((size_t)(b * 2048 + row)) * 512 + h * 64;
            #pragma unroll
            for (int dsub = 0; dsub < 4; ++dsub) {
                float4 p4 = *(const float4*)&smem.p2.Obuf[w4][(qs * 16 + l15) * 68 + dsub * 16 + quad * 4];
                ushort4 hv;
                hv.x = rnebf((oacc[qs][dsub][0] + p4.x) * inv);
                hv.y = rnebf((oacc[qs][dsub][1] + p4.y) * inv);
                hv.z = rnebf((oacc[qs][dsub][2] + p4.z) * inv);
                hv.w = rnebf((oacc[qs][dsub][3] + p4.w) * inv);
                *(ushort4*)&rp[dsub * 16 + quad * 4] = hv;
            }
        }
    }
}

extern "C" void kernel_launch(void* const* d_in, const int* in_sizes, int n_in,
                              void* d_out, int out_size, void* d_ws, size_t ws_size,
                              hipStream_t stream) {
    const float* query = (const float*)d_in[0];
    const float* key   = (const float*)d_in[1];
    const float* value = (const float*)d_in[2];
    const int*   mask  = (const int*)d_in[3];
    const float* Wq = (const float*)d_in[4];
    const float* bq = (const float*)d_in[5];
    const float* Wk = (const float*)d_in[6];
    const float* bk = (const float*)d_in[7];
    const float* Wv = (const float*)d_in[8];
    const float* bv = (const float*)d_in[9];
    const float* Wo = (const float*)d_in[10];
    const float* bo = (const float*)d_in[11];

    char* w = (char*)d_ws;
    const size_t MB = (size_t)1 << 20;
    ushort* Qh  = (ushort*)(w + 0 * MB);    // 8 MB
    ushort* XS  = (ushort*)(w + 8 * MB);    // 8 MB (attn out, single RNE plane)
    ushort* Khp = (ushort*)(w + 16 * MB);   // 8 MB
    ushort* VhT = (ushort*)(w + 24 * MB);   // 8 MB
    ushort* WTh = (ushort*)(w + 32 * MB);   // [2048][512] = 2 MB (z=0..3: Wq,Wk,Wv,Wo)
    ushort* WTl = (ushort*)(w + 34 * MB);   // 2 MB
    int* idxbuf = (int*)(w + 36 * MB);      // [4][2048] int, 32 KB
    int* nvbuf  = (int*)(w + 36 * MB + 65536);
    ushort* Xr  = (ushort*)(w + 40 * MB);   // [3][8192][512] bf16 = 24 MB

    prep_kernel<<<dim3(2048, 1, 4), 256, 0, stream>>>(
        Wq, Wk, Wv, Wo, WTh, WTl, mask, idxbuf, nvbuf, query, key, value, Xr);
    gemmqkv_kernel<<<dim3(64, 12), 256, 0, stream>>>(
        Xr, idxbuf, nvbuf, WTh, bq, bk, bv, Qh, Khp, VhT);
    attn3_kernel<<<dim3(32, 8), 512, 0, stream>>>(Qh, Khp, VhT, nvbuf, XS);
    gemmo_kernel<<<dim3(64, 4), 256, 0, stream>>>(
        XS, WTh + (size_t)1536 * 512, WTl + (size_t)1536 * 512, bo, (float*)d_out);
}